// Round 8
// baseline (127.512 us; speedup 1.0000x reference)
//
#include <hip/hip_runtime.h>

// KPN per-pixel 5x5 predicted convolution, channels-last fp32.
// out[b,h,w,c] = sum_{i,j} feat[b,h+i-2,w+j-2,c] * kernel[b,h,w,i*5+j] + bias[c]
//
// Round 8: hybrid. R5 (global feat, deep MLP, 2 waves/SIMD) and R7 (LDS feat
// tile, async staging) BOTH plateau ~35 us: R5 latency-starved, R7 LDS/barrier
// phase-bound. This round: register-resident feat with more reuse + occupancy.
//  - VH=8 rows/thread: 12 row-loads x 5 cols = 60 f4 loads / 8 outputs
//    (7.5/output vs R5's 10). acc = 8 float4 = 32 VGPR.
//  - TW=16, 128-thread blocks, __launch_bounds__(128,3): VGPR cap ~168
//    (R4 lesson: default cap spills; R5 showed 256-cap works) -> 12 waves/CU.
//  - Weights: async DMA -> LDS [oh][wL][25] (zero-conflict: 8 wL-lanes at
//    stride 25 -> distinct banks; 8 cg-lanes broadcast). OOB taps zeroed in
//    LDS for edge blocks only -> compute loop fully maskless, feat addresses
//    clamped (garbage * 0 = 0).

#define BB 4
#define HH 256
#define WW 256
#define CC 32
#define KK 5
#define VH 8                   // output rows per thread/block
#define TW 16                  // tile width (pixels)
#define TPB 128
#define TROWS (VH + KK - 1)    // 12 feat rows touched
#define NW  (VH * TW * KK * KK)        // 3200 weight floats
#define NW4 (NW / 4)                   // 800 float4
#define NQ  13                          // ceil(800/64) DMA issues

typedef __attribute__((address_space(1))) const void gvoid_t;
typedef __attribute__((address_space(3))) void svoid_t;

__global__ __launch_bounds__(TPB, 3) void kpn_conv_kernel(
    const float* __restrict__ feat,
    const float* __restrict__ kern,
    const float* __restrict__ bias,
    float* __restrict__ out)
{
    __shared__ float4 skw4[NQ * 64];   // 832 f4 = 13.3 KB (800 + DMA tail pad)
    float* const skw = (float*)skw4;

    const int t    = threadIdx.x;
    const int lane = t & 63;
    const int wave = t >> 6;

    const int bw = blockIdx.x & 15;           // W/TW = 16
    const int bh = (blockIdx.x >> 4) & 31;    // H/VH = 32
    const int b  = blockIdx.x >> 9;           // B = 4
    const int h0 = bh * VH;
    const int w0 = bw * TW;

    // ---- Async-stage weights: 13 wave-issues, no VGPR payload. ----
    // Per output row oh: 16 px * 25 taps = 400 floats (100 f4) contiguous.
    {
        const float* kb = kern + (size_t)((b * HH + h0) * WW + w0) * (KK * KK);
        #pragma unroll
        for (int q = wave; q < NQ; q += TPB / 64) {
            int e   = (q << 6) + lane;
            int e4  = min(e, NW4 - 1);        // tail lanes duplicate into pad
            int oh  = e4 / 100;
            int off = (e4 - oh * 100) << 2;
            const float* gp = kb + (size_t)oh * (WW * KK * KK) + off;
            __builtin_amdgcn_global_load_lds((gvoid_t*)gp,
                                             (svoid_t*)(skw4 + (q << 6)),
                                             16, 0, 0);
        }
    }
    __syncthreads();   // drain DMA

    // ---- Edge blocks only: zero OOB taps in LDS (block-uniform branch). ----
    if (bh == 0 || bh == (HH / VH - 1) || bw == 0 || bw == (WW / TW - 1)) {
        for (int e = t; e < NW; e += TPB) {
            int oh  = e / (TW * KK * KK);          // /400
            int rem = e - oh * (TW * KK * KK);
            int wl  = rem / (KK * KK);             // /25
            int tap = rem - wl * (KK * KK);
            int i   = tap / KK;
            int j   = tap - i * KK;
            int hh  = h0 + oh + i - (KK / 2);
            int ww  = w0 + wl + j - (KK / 2);
            if (((unsigned)hh >= (unsigned)HH) || ((unsigned)ww >= (unsigned)WW))
                skw[e] = 0.0f;
        }
        __syncthreads();
    }

    // ---- Maskless compute: feat register-resident, clamped addresses. ----
    const int cg = (t & 7) << 2;   // channel group
    const int wL = t >> 3;         // 0..15
    const float* fb = feat + (((size_t)b) << 16) * CC;

    int wc[KK];
    #pragma unroll
    for (int j = 0; j < KK; ++j)
        wc[j] = min(max(w0 + wL + j - (KK / 2), 0), WW - 1);

    const float4 bz = *(const float4*)(bias + cg);
    float4 acc[VH];
    #pragma unroll
    for (int oh = 0; oh < VH; ++oh) acc[oh] = bz;

    #pragma unroll
    for (int r = 0; r < TROWS; ++r) {              // 12 rows, branch-free
        const int hh = min(max(h0 + r - (KK / 2), 0), HH - 1);
        const float* rp = fb + (((size_t)hh) << 13);

        float4 f[KK];
        #pragma unroll
        for (int j = 0; j < KK; ++j)
            f[j] = *(const float4*)(rp + (wc[j] << 5) + cg);

        #pragma unroll
        for (int oh = 0; oh < VH; ++oh) {
            const int i = r - oh;                  // kernel row
            if (i >= 0 && i < KK) {                // compile-time after unroll
                const float* wp = skw + (oh * TW + wL) * (KK * KK) + i * KK;
                const float wg0 = wp[0], wg1 = wp[1], wg2 = wp[2],
                            wg3 = wp[3], wg4 = wp[4];
                acc[oh].x += f[0].x*wg0 + f[1].x*wg1 + f[2].x*wg2 + f[3].x*wg3 + f[4].x*wg4;
                acc[oh].y += f[0].y*wg0 + f[1].y*wg1 + f[2].y*wg2 + f[3].y*wg3 + f[4].y*wg4;
                acc[oh].z += f[0].z*wg0 + f[1].z*wg1 + f[2].z*wg2 + f[3].z*wg3 + f[4].z*wg4;
                acc[oh].w += f[0].w*wg0 + f[1].w*wg1 + f[2].w*wg2 + f[3].w*wg3 + f[4].w*wg4;
            }
        }
    }

    // ---- Coalesced stores: 8 rows x 1 KiB per wave. ----
    #pragma unroll
    for (int oh = 0; oh < VH; ++oh) {
        const size_t pix = (size_t)(b * HH + h0 + oh) * WW + (w0 + wL);
        *(float4*)(out + pix * CC + cg) = acc[oh];
    }
}

extern "C" void kernel_launch(void* const* d_in, const int* in_sizes, int n_in,
                              void* d_out, int out_size, void* d_ws, size_t ws_size,
                              hipStream_t stream) {
    const float* feat = (const float*)d_in[0];
    const float* kern = (const float*)d_in[1];
    const float* bias = (const float*)d_in[2];
    float* out = (float*)d_out;

    dim3 grid(BB * (HH / VH) * (WW / TW));  // 2048 blocks
    dim3 block(TPB);
    kpn_conv_kernel<<<grid, block, 0, stream>>>(feat, kern, bias, out);
}